// Round 7
// baseline (580.826 us; speedup 1.0000x reference)
//
#include <hip/hip_runtime.h>
#include <hip/hip_bf16.h>

using bf16 = __hip_bfloat16;
typedef float f32x4 __attribute__((ext_vector_type(4)));
typedef short s16x8 __attribute__((ext_vector_type(8)));
typedef short s16x4 __attribute__((ext_vector_type(4)));

#define B_N   8
#define C_N   512
#define HW_N  1024
#define LC_N  1024
#define HID_N 512
#define DHEAD 64
#define EPSN  1e-6f
#define NBLK  512

__device__ __forceinline__ f32x4 mfma16(s16x8 a, s16x8 b, f32x4 c) {
  return __builtin_amdgcn_mfma_f32_16x16x32_bf16(a, b, c, 0, 0, 0);
}
__device__ __forceinline__ void gload_lds16(const void* g, void* l) {
  __builtin_amdgcn_global_load_lds((const __attribute__((address_space(1))) void*)g,
                                   (__attribute__((address_space(3))) void*)l, 16, 0, 0);
}
__device__ __forceinline__ s16x8 ld8(const bf16* p) {
  return *reinterpret_cast<const s16x8*>(p);
}
__device__ __forceinline__ unsigned short bfbits(float f) {
  return __builtin_bit_cast(unsigned short, __float2bfloat16(f));
}

// device-scope grid barrier: counter + generation (bar[0]=cnt, bar[1]=gen).
// Zeroed by init_kernel each call. Grid of NBLK blocks is guaranteed co-resident
// (512 = 2/CU x 256 CU; LDS 50K*2<160K, VGPR capped by launch_bounds).
__device__ __forceinline__ void grid_barrier(int* bar) {
  __syncthreads();
  if (threadIdx.x == 0) {
    __threadfence();   // make this block's global stores device-visible
    int g = __hip_atomic_load(&bar[1], __ATOMIC_RELAXED, __HIP_MEMORY_SCOPE_AGENT);
    int v = __hip_atomic_fetch_add(&bar[0], 1, __ATOMIC_ACQ_REL, __HIP_MEMORY_SCOPE_AGENT);
    if (v == NBLK - 1) {
      __hip_atomic_store(&bar[0], 0, __ATOMIC_RELAXED, __HIP_MEMORY_SCOPE_AGENT);
      __hip_atomic_fetch_add(&bar[1], 1, __ATOMIC_ACQ_REL, __HIP_MEMORY_SCOPE_AGENT);
    } else {
      while (__hip_atomic_load(&bar[1], __ATOMIC_ACQUIRE, __HIP_MEMORY_SCOPE_AGENT) == g)
        __builtin_amdgcn_s_sleep(2);
    }
  }
  __syncthreads();
}

// ---------------- init: zero ssq accumulators + barrier state ----------------
__global__ __launch_bounds__(256) void init_kernel(
    float* __restrict__ ssqx, float* __restrict__ ssqy, int* __restrict__ bar)
{
  int i = blockIdx.x * 256 + threadIdx.x;
  if (i < 8192) { ssqx[i] = 0.f; ssqy[i] = 0.f; }
  if (i < 8) bar[i] = 0;
}

// ---------------- shared GEMM core: 128x128, BK=32, 2-phase dbuf, slot-XOR swizzle ----
__device__ __forceinline__ void gemm128_core(
    const bf16* __restrict__ A, const bf16* __restrict__ W, int K, int m0, int n0,
    bf16* sA, bf16* sB, f32x4 (&acc)[4][4])
{
  const int t = threadIdx.x;
  const int lane = t & 63, w = t >> 6;
  const int wm = (w >> 1) * 64, wn = (w & 1) * 64;
  const int lr = lane & 15, hi = lane >> 4;
  const int r = t >> 2, seg = t & 3;
  const int segsw = seg ^ ((r >> 1) & 3);           // inverse-swizzled global slot
  const long aoff0 = (long)(m0 + r) * K + segsw * 8;
  const long aoff1 = (long)(m0 + 64 + r) * K + segsw * 8;
  const long woff0 = (long)(n0 + r) * K + segsw * 8;
  const long woff1 = (long)(n0 + 64 + r) * K + segsw * 8;
  const int d0 = r * 32 + seg * 8, d1 = (64 + r) * 32 + seg * 8;  // linear LDS dest
  const int kofs = (hi ^ ((lr >> 1) & 3)) * 8;      // swizzled read slot

#define GSTAGE(buf, k0)                                           \
  do {                                                            \
    gload_lds16(A + aoff0 + (k0), &sA[(buf) * 4096 + d0]);        \
    gload_lds16(A + aoff1 + (k0), &sA[(buf) * 4096 + d1]);        \
    gload_lds16(W + woff0 + (k0), &sB[(buf) * 4096 + d0]);        \
    gload_lds16(W + woff1 + (k0), &sB[(buf) * 4096 + d1]);        \
  } while (0)

  GSTAGE(0, 0);
  __syncthreads();
  int cur = 0;
  for (int k0 = 0; k0 < K; k0 += 32) {
    if (k0 + 32 < K) GSTAGE(cur ^ 1, k0 + 32);
    s16x8 af[4], bfr[4];
#pragma unroll
    for (int mi = 0; mi < 4; ++mi)
      af[mi] = *reinterpret_cast<const s16x8*>(
          &sA[cur * 4096 + (wm + mi * 16 + lr) * 32 + kofs]);
#pragma unroll
    for (int ni = 0; ni < 4; ++ni)
      bfr[ni] = *reinterpret_cast<const s16x8*>(
          &sB[cur * 4096 + (wn + ni * 16 + lr) * 32 + kofs]);
    __builtin_amdgcn_s_setprio(1);
#pragma unroll
    for (int mi = 0; mi < 4; ++mi)
#pragma unroll
      for (int ni = 0; ni < 4; ++ni)
        acc[mi][ni] = mfma16(af[mi], bfr[ni], acc[mi][ni]);
    __builtin_amdgcn_s_setprio(0);
    __syncthreads();
    cur ^= 1;
  }
#undef GSTAGE
}

// ---------------- the mega kernel: all 5 stages, 4 grid barriers ----------------
__global__ __launch_bounds__(256, 3)
void mega(const float* __restrict__ x, const float* __restrict__ ctx,
          const float* __restrict__ Wq, const float* __restrict__ Wkv,
          const float* __restrict__ Wo, const float* __restrict__ bo,
          const float* __restrict__ g, const float* __restrict__ g2,
          bf16* __restrict__ Wqg, bf16* __restrict__ Wkvg, bf16* __restrict__ Wob,
          float* __restrict__ ssqx, float* __restrict__ ssqy,
          bf16* __restrict__ xbf, bf16* __restrict__ cnbf,
          bf16* __restrict__ qbf, bf16* __restrict__ kvbf, bf16* __restrict__ vT,
          bf16* __restrict__ attno, float* __restrict__ ytmp,
          float* __restrict__ out, int* __restrict__ bar)
{
  __shared__ __align__(16) char smem[51200];
  const int vb = blockIdx.x;
  const int tid = threadIdx.x;

  // ========== S0: weight prep + x transpose/ssq + context RMSNorm ==========
  for (int t = vb; t < 4096; t += NBLK) {             // prep weights
    int idx = t * 256 + tid;
    const int NQ = 512 * 512, NKV = 1024 * 512;
    if (idx < NQ) {
      Wqg[idx] = __float2bfloat16(Wq[idx] * g[idx & 511]);
    } else if (idx < NQ + NKV) {
      int j = idx - NQ;
      Wkvg[j] = __float2bfloat16(Wkv[j] * g[j & 511]);
    } else {
      int j = idx - NQ - NKV;
      Wob[j] = __float2bfloat16(Wo[j]);
    }
  }
  {
    float* tile = (float*)smem;                       // [32][33]
    float* part = (float*)(smem + 4352);              // [8][32]
    int tx = tid & 31, ty = tid >> 5;
    for (int t = vb; t < 4096; t += NBLK) {           // xbf transpose + ssqx
      int b = t >> 9, cy = (t >> 5) & 15, px = t & 31;
      int c0 = cy * 32, p0 = px * 32;
#pragma unroll
      for (int j = 0; j < 4; ++j) {
        int c = ty + j * 8;
        tile[c * 33 + tx] = x[((long)b * C_N + c0 + c) * HW_N + p0 + tx];
      }
      __syncthreads();
      {
        float s = 0.f;
#pragma unroll
        for (int i = 0; i < 4; ++i) {
          float v = tile[(ty * 4 + i) * 33 + tx];
          s += v * v;
        }
        part[ty * 32 + tx] = s;
      }
#pragma unroll
      for (int j = 0; j < 4; ++j) {
        int p = ty + j * 8;
        xbf[((long)b * HW_N + p0 + p) * C_N + c0 + tx] = __float2bfloat16(tile[tx * 33 + p]);
      }
      __syncthreads();
      if (ty == 0) {
        float tot = 0.f;
#pragma unroll
        for (int i = 0; i < 8; ++i) tot += part[i * 32 + tx];
        atomicAdd(&ssqx[b * HW_N + p0 + tx], tot);
      }
    }
  }
  for (int t = vb; t < 2048; t += NBLK) {             // ctx RMSNorm
    int row = t * 4 + (tid >> 6);
    int lane = tid & 63;
    const float* cr = ctx + (long)row * C_N;
    float4 v0 = ((const float4*)cr)[lane * 2];
    float4 v1 = ((const float4*)cr)[lane * 2 + 1];
    float s = v0.x*v0.x + v0.y*v0.y + v0.z*v0.z + v0.w*v0.w
            + v1.x*v1.x + v1.y*v1.y + v1.z*v1.z + v1.w*v1.w;
#pragma unroll
    for (int m = 1; m < 64; m <<= 1) s += __shfl_xor(s, m);
    float r = rsqrtf(s * (1.0f / C_N) + EPSN);
    bf16 tmp[8];
    tmp[0] = __float2bfloat16(v0.x * r); tmp[1] = __float2bfloat16(v0.y * r);
    tmp[2] = __float2bfloat16(v0.z * r); tmp[3] = __float2bfloat16(v0.w * r);
    tmp[4] = __float2bfloat16(v1.x * r); tmp[5] = __float2bfloat16(v1.y * r);
    tmp[6] = __float2bfloat16(v1.z * r); tmp[7] = __float2bfloat16(v1.w * r);
    *reinterpret_cast<s16x8*>(cnbf + (long)row * C_N + lane * 8) =
        *reinterpret_cast<const s16x8*>(tmp);
  }
  grid_barrier(bar);

  // ========== S1: Q + KV projection GEMMs (768 tiles over 512 blocks) ==========
  {
    bf16* sA = (bf16*)smem;                           // 2 x 4096 elems
    bf16* sB = (bf16*)(smem + 16384);
    const int lane = tid & 63, w = tid >> 6;
    const int wm = (w >> 1) * 64, wn = (w & 1) * 64;
    const int lr = lane & 15, hi = lane >> 4;
    for (int tv = vb; tv < 768; tv += NBLK) {
      const bf16 *A, *W;
      int m0, n0;
      bool isQ;
      if (tv < 256) {
        isQ = true;  A = xbf;  W = Wqg;
        m0 = (tv >> 2) * 128; n0 = (tv & 3) * 128;
      } else {
        isQ = false; A = cnbf; W = Wkvg;
        int b2 = tv - 256;
        m0 = (b2 >> 3) * 128; n0 = (b2 & 7) * 128;
      }
      f32x4 acc[4][4] = {};
      gemm128_core(A, W, C_N, m0, n0, sA, sB, acc);
#pragma unroll
      for (int mi = 0; mi < 4; ++mi) {
#pragma unroll
        for (int rr = 0; rr < 4; ++rr) {
          int row = m0 + wm + mi * 16 + hi * 4 + rr;
          float rsc = 0.f;
          if (isQ)   // per-pixel RMS scale commutes with GEMM; 0.125*log2(e) folded
            rsc = rsqrtf(ssqx[row] * (1.0f / C_N) + EPSN) * 0.18033688011112042f;
#pragma unroll
          for (int ni = 0; ni < 4; ++ni) {
            int col = n0 + wn + ni * 16 + lr;
            float v = acc[mi][ni][rr];
            if (isQ) {
              qbf[(long)row * HID_N + col] = __float2bfloat16(v * rsc);
            } else if (col < HID_N) {
              kvbf[(long)row * (2 * HID_N) + col] = __float2bfloat16(v);
            } else {
              int b = row >> 10, l = row & 1023;
              vT[((long)b * HID_N + (col - HID_N)) * LC_N + l] = __float2bfloat16(v);
            }
          }
        }
      }
    }
  }
  grid_barrier(bar);

  // ========== S2: fused flash attention (512 blocks 1:1) ==========
  {
    bf16* sK = (bf16*)smem;                           // [2][4096] flat
    bf16* sV = (bf16*)(smem + 16384);
    bf16* Pl = (bf16*)(smem + 32768);                 // [4][32*72]
    const int wv = tid >> 6, lane = tid & 63;
    const int lr = lane & 15, hi = lane >> 4;
    const int hi8 = hi * 8, hi4 = hi * 4;
    const int bh = vb & 63, b = bh >> 3, h = bh & 7;  // vb%8 == bh%8 -> XCD locality
    const int q_base = (vb >> 6) * 128 + wv * 32;

    const bf16* kbase = kvbf + (long)b * LC_N * 1024 + h * DHEAD;
    const bf16* vbase = vT + ((long)b * HID_N + h * DHEAD) * (long)LC_N;
    bf16* Pw = Pl + wv * (32 * 72);

    s16x8 qf[2][2];
#pragma unroll
    for (int qt = 0; qt < 2; ++qt)
#pragma unroll
      for (int c = 0; c < 2; ++c)
        qf[qt][c] = ld8(qbf + ((long)b * HW_N + q_base + qt * 16 + lr) * HID_N
                            + h * DHEAD + c * 32 + hi8);

    const int srow = lane >> 2;
    const int scol = ((lane & 3) ^ ((lane >> 3) & 3)) * 8;  // inverse-swizzled source
    const int rxofs = (hi ^ ((lr >> 1) & 3)) * 8;           // swizzled read slot

#define ASTAGE(buf, l0n)                                                          \
    do {                                                                          \
      _Pragma("unroll")                                                           \
      for (int j = 0; j < 4; ++j) {                                               \
        int lin = wv * 4 + j;                                                     \
        int cc = (lin >> 2) & 1, qq = lin & 3;                                    \
        if (lin < 8) {                                                            \
          gload_lds16(kbase + (long)((l0n) + qq * 16 + srow) * 1024 + cc * 32 + scol, \
                      &sK[(buf) * 4096 + cc * 2048 + qq * 512 + lane * 8]);       \
        } else {                                                                  \
          gload_lds16(vbase + (long)(qq * 16 + srow) * 1024 + (l0n) + cc * 32 + scol, \
                      &sV[(buf) * 4096 + cc * 2048 + qq * 512 + lane * 8]);       \
        }                                                                         \
      }                                                                           \
    } while (0)

    float m[2] = {-1e30f, -1e30f};
    float lsum[2] = {0.f, 0.f};
    f32x4 o[2][4] = {};

    ASTAGE(0, 0);
    __syncthreads();
    int cur = 0;

#pragma unroll 1
    for (int l0 = 0; l0 < LC_N; l0 += 64) {
      if (l0 + 64 < LC_N) ASTAGE(cur ^ 1, l0 + 64);

      f32x4 st[4][2] = {};
      __builtin_amdgcn_s_setprio(1);
#pragma unroll
      for (int kt = 0; kt < 4; ++kt) {
        s16x8 k0 = *reinterpret_cast<const s16x8*>(
            &sK[cur * 4096 + (kt * 16 + lr) * 32 + rxofs]);
        s16x8 k1 = *reinterpret_cast<const s16x8*>(
            &sK[cur * 4096 + 2048 + (kt * 16 + lr) * 32 + rxofs]);
        st[kt][0] = mfma16(k0, qf[0][0], st[kt][0]);
        st[kt][0] = mfma16(k1, qf[0][1], st[kt][0]);
        st[kt][1] = mfma16(k0, qf[1][0], st[kt][1]);
        st[kt][1] = mfma16(k1, qf[1][1], st[kt][1]);
      }
      __builtin_amdgcn_s_setprio(0);

      float pmax[2];
#pragma unroll
      for (int qt = 0; qt < 2; ++qt) {
        float mx = st[0][qt][0];
#pragma unroll
        for (int kt = 0; kt < 4; ++kt)
#pragma unroll
          for (int rr = 0; rr < 4; ++rr)
            mx = fmaxf(mx, st[kt][qt][rr]);
        pmax[qt] = mx;
      }
      bool ok = (pmax[0] <= m[0] + 8.f) && (pmax[1] <= m[1] + 8.f);
      if (!__all(ok)) {
#pragma unroll
        for (int qt = 0; qt < 2; ++qt) {
          float rm = pmax[qt];
          rm = fmaxf(rm, __shfl_xor(rm, 16));
          rm = fmaxf(rm, __shfl_xor(rm, 32));
          float mn = fmaxf(m[qt], rm);
          float al = __builtin_amdgcn_exp2f(m[qt] - mn);
          m[qt] = mn;
          lsum[qt] *= al;
          float arr[4];
#pragma unroll
          for (int rr = 0; rr < 4; ++rr) arr[rr] = __shfl(al, hi4 + rr);
#pragma unroll
          for (int dt = 0; dt < 4; ++dt)
#pragma unroll
            for (int rr = 0; rr < 4; ++rr) o[qt][dt][rr] *= arr[rr];
        }
      }

#pragma unroll
      for (int qt = 0; qt < 2; ++qt) {
        float ls = 0.f;
#pragma unroll
        for (int kt = 0; kt < 4; ++kt) {
          float p0 = __builtin_amdgcn_exp2f(st[kt][qt][0] - m[qt]);
          float p1 = __builtin_amdgcn_exp2f(st[kt][qt][1] - m[qt]);
          float p2 = __builtin_amdgcn_exp2f(st[kt][qt][2] - m[qt]);
          float p3 = __builtin_amdgcn_exp2f(st[kt][qt][3] - m[qt]);
          ls += (p0 + p1) + (p2 + p3);
          s16x4 pk;
          pk[0] = (short)bfbits(p0); pk[1] = (short)bfbits(p1);
          pk[2] = (short)bfbits(p2); pk[3] = (short)bfbits(p3);
          *reinterpret_cast<s16x4*>(&Pw[(qt * 16 + lr) * 72 + kt * 16 + hi4]) = pk;
        }
        lsum[qt] += ls;
      }

      __builtin_amdgcn_s_setprio(1);
#pragma unroll
      for (int c = 0; c < 2; ++c) {
        s16x8 pa0 = *reinterpret_cast<const s16x8*>(&Pw[(0 * 16 + lr) * 72 + c * 32 + hi8]);
        s16x8 pa1 = *reinterpret_cast<const s16x8*>(&Pw[(1 * 16 + lr) * 72 + c * 32 + hi8]);
#pragma unroll
        for (int dt = 0; dt < 4; ++dt) {
          s16x8 vv = *reinterpret_cast<const s16x8*>(
              &sV[cur * 4096 + c * 2048 + (dt * 16 + lr) * 32 + rxofs]);
          o[0][dt] = mfma16(pa0, vv, o[0][dt]);
          o[1][dt] = mfma16(pa1, vv, o[1][dt]);
        }
      }
      __builtin_amdgcn_s_setprio(0);

      __syncthreads();
      cur ^= 1;
    }
#undef ASTAGE

#pragma unroll
    for (int qt = 0; qt < 2; ++qt) {
      float ls = lsum[qt];
      ls += __shfl_xor(ls, 16);
      ls += __shfl_xor(ls, 32);
      float linv[4];
#pragma unroll
      for (int rr = 0; rr < 4; ++rr) linv[rr] = 1.f / __shfl(ls, hi4 + rr);
#pragma unroll
      for (int dt = 0; dt < 4; ++dt)
#pragma unroll
        for (int rr = 0; rr < 4; ++rr)
          attno[((long)b * HW_N + q_base + qt * 16 + hi4 + rr) * HID_N
                + h * DHEAD + dt * 16 + lr] = __float2bfloat16(o[qt][dt][rr] * linv[rr]);
    }
  }
  grid_barrier(bar);

  // ========== S3: O-projection GEMM + bias + row ssq (256 tiles) ==========
  if (vb < 256) {
    bf16* sA = (bf16*)smem;
    bf16* sB = (bf16*)(smem + 16384);
    const int m0 = (vb >> 2) * 128;
    const int n0 = (vb & 3) * 128;
    f32x4 acc[4][4] = {};
    gemm128_core(attno, Wob, HID_N, m0, n0, sA, sB, acc);

    const int lane = tid & 63, w = tid >> 6;
    const int wm = (w >> 1) * 64, wn = (w & 1) * 64;
    const int lr = lane & 15, hi = lane >> 4;
    float ss[4][4];
#pragma unroll
    for (int mi = 0; mi < 4; ++mi)
#pragma unroll
      for (int rr = 0; rr < 4; ++rr) ss[mi][rr] = 0.f;
#pragma unroll
    for (int mi = 0; mi < 4; ++mi) {
#pragma unroll
      for (int ni = 0; ni < 4; ++ni) {
        float bb = bo[n0 + wn + ni * 16 + lr];
#pragma unroll
        for (int rr = 0; rr < 4; ++rr) {
          int row = m0 + wm + mi * 16 + hi * 4 + rr;
          int col = n0 + wn + ni * 16 + lr;
          float v = acc[mi][ni][rr] + bb;
          ytmp[(long)row * C_N + col] = v;
          ss[mi][rr] += v * v;
        }
      }
    }
#pragma unroll
    for (int mi = 0; mi < 4; ++mi)
#pragma unroll
      for (int rr = 0; rr < 4; ++rr) {
        float s = ss[mi][rr];
        s += __shfl_xor(s, 1); s += __shfl_xor(s, 2);
        s += __shfl_xor(s, 4); s += __shfl_xor(s, 8);
        if (lr == 0) atomicAdd(&ssqy[m0 + wm + mi * 16 + hi * 4 + rr], s);
      }
  }
  grid_barrier(bar);

  // ========== S4: final transpose + norm + residual ==========
  {
    float* tile = (float*)smem;                       // [32][33]
    int tx = tid & 31, ty = tid >> 5;
    for (int t = vb; t < 4096; t += NBLK) {
      int b = t >> 9, cy = (t >> 5) & 15, px = t & 31;
      int c0 = cy * 32, p0 = px * 32;
#pragma unroll
      for (int j = 0; j < 4; ++j) {
        int p = ty + j * 8;
        tile[p * 33 + tx] = ytmp[((long)b * HW_N + p0 + p) * C_N + c0 + tx];
      }
      __syncthreads();
      float r = rsqrtf(ssqy[b * HW_N + p0 + tx] * (1.0f / C_N) + EPSN);
#pragma unroll
      for (int j = 0; j < 4; ++j) {
        int c = ty + j * 8;
        long oidx = ((long)b * C_N + c0 + c) * HW_N + p0 + tx;
        out[oidx] = tile[tx * 33 + c] * r * g2[c0 + c] + x[oidx];
      }
      __syncthreads();
    }
  }
}

// ---------------- launch ----------------
extern "C" void kernel_launch(void* const* d_in, const int* in_sizes, int n_in,
                              void* d_out, int out_size, void* d_ws, size_t ws_size,
                              hipStream_t stream) {
  const float* x   = (const float*)d_in[0];
  const float* ctx = (const float*)d_in[1];
  const float* Wq  = (const float*)d_in[2];
  const float* Wkv = (const float*)d_in[3];
  const float* Wo  = (const float*)d_in[4];
  const float* bo  = (const float*)d_in[5];
  const float* g   = (const float*)d_in[6];
  const float* g2  = (const float*)d_in[7];
  float* out = (float*)d_out;

  char* ws = (char*)d_ws;
  bf16*  Wqg   = (bf16*)(ws + 0);          //  524288
  bf16*  Wkvg  = (bf16*)(ws + 524288);     // 1048576
  bf16*  Wob   = (bf16*)(ws + 1572864);    //  524288
  float* ssqx  = (float*)(ws + 2097152);   //  32768
  float* ssqy  = (float*)(ws + 2129920);   //  32768
  int*   bar   = (int*)  (ws + 2162688);   //  64 (+pad)
  bf16*  xbf   = (bf16*)(ws + 2163712);    // 8388608
  bf16*  cnbf  = (bf16*)(ws + 10552320);   // 8388608
  bf16*  qbf   = (bf16*)(ws + 18940928);   // 8388608
  bf16*  kvbf  = (bf16*)(ws + 27329536);   // 16777216
  bf16*  vT    = (bf16*)(ws + 44106752);   // 8388608
  bf16*  attno = (bf16*)(ws + 52495360);   // 8388608
  float* ytmp  = (float*)(ws + 2163712);   // aliases xbf+cnbf (dead by S3)

  init_kernel<<<32, 256, 0, stream>>>(ssqx, ssqy, bar);
  mega<<<NBLK, 256, 0, stream>>>(x, ctx, Wq, Wkv, Wo, bo, g, g2,
                                 Wqg, Wkvg, Wob, ssqx, ssqy,
                                 xbf, cnbf, qbf, kvbf, vT, attno,
                                 ytmp, out, bar);
}

// Round 8
// 170.297 us; speedup vs baseline: 3.4107x; 3.4107x over previous
//
#include <hip/hip_runtime.h>
#include <hip/hip_bf16.h>

using bf16 = __hip_bfloat16;
typedef float f32x4 __attribute__((ext_vector_type(4)));
typedef short s16x8 __attribute__((ext_vector_type(8)));
typedef short s16x4 __attribute__((ext_vector_type(4)));

#define B_N   8
#define C_N   512
#define HW_N  1024
#define LC_N  1024
#define HID_N 512
#define DHEAD 64
#define EPSN  1e-6f

__device__ __forceinline__ f32x4 mfma16(s16x8 a, s16x8 b, f32x4 c) {
  return __builtin_amdgcn_mfma_f32_16x16x32_bf16(a, b, c, 0, 0, 0);
}
__device__ __forceinline__ void gload_lds16(const void* g, void* l) {
  __builtin_amdgcn_global_load_lds((const __attribute__((address_space(1))) void*)g,
                                   (__attribute__((address_space(3))) void*)l, 16, 0, 0);
}
__device__ __forceinline__ s16x8 ld8(const bf16* p) {
  return *reinterpret_cast<const s16x8*>(p);
}
__device__ __forceinline__ unsigned short bfbits(float f) {
  return __builtin_bit_cast(unsigned short, __float2bfloat16(f));
}

// ---------------- K0: zero ssq accumulators (ws is 0xAA-poisoned every call) ----------
__global__ __launch_bounds__(256) void init_kernel(
    float* __restrict__ ssqx, float* __restrict__ ssqy)
{
  int i = blockIdx.x * 256 + threadIdx.x;
  if (i < 8192) { ssqx[i] = 0.f; ssqy[i] = 0.f; }
}

// ---------------- K1: pre — weights prep | x transpose + ssqx | ctx RMSNorm ----------
// blocks [0,4096): weight fold+cast; [4096,8192): xbf tiles; [8192,10240): ctxnorm rows
__global__ __launch_bounds__(256) void pre_kernel(
    const float* __restrict__ x, const float* __restrict__ ctx,
    const float* __restrict__ Wq, const float* __restrict__ Wkv,
    const float* __restrict__ Wo, const float* __restrict__ g,
    bf16* __restrict__ Wqg, bf16* __restrict__ Wkvg, bf16* __restrict__ Wob,
    bf16* __restrict__ xbf, bf16* __restrict__ cnbf, float* __restrict__ ssqx)
{
  __shared__ float sm[1056 + 256];                    // tile[32][33] + part[8][32]
  const int bid = blockIdx.x, tid = threadIdx.x;

  if (bid < 4096) {                                   // ---- weights ----
    int idx = bid * 256 + tid;
    const int NQ = 512 * 512, NKV = 1024 * 512;
    if (idx < NQ) {
      Wqg[idx] = __float2bfloat16(Wq[idx] * g[idx & 511]);
    } else if (idx < NQ + NKV) {
      int j = idx - NQ;
      Wkvg[j] = __float2bfloat16(Wkv[j] * g[j & 511]);
    } else {
      int j = idx - NQ - NKV;
      Wob[j] = __float2bfloat16(Wo[j]);
    }
  } else if (bid < 8192) {                            // ---- xbf transpose + ssqx ----
    float* tile = sm;                                 // [32][33]
    float* part = sm + 1056;                          // [8][32]
    int t = bid - 4096;
    int b = t >> 9, c0 = ((t >> 5) & 15) * 32, p0 = (t & 31) * 32;
    int tx = tid & 31, ty = tid >> 5;
#pragma unroll
    for (int j = 0; j < 4; ++j) {
      int c = ty + j * 8;
      tile[c * 33 + tx] = x[((long)b * C_N + c0 + c) * HW_N + p0 + tx];
    }
    __syncthreads();
    {
      float s = 0.f;
#pragma unroll
      for (int i = 0; i < 4; ++i) {
        float v = tile[(ty * 4 + i) * 33 + tx];
        s += v * v;
      }
      part[ty * 32 + tx] = s;
    }
#pragma unroll
    for (int j = 0; j < 4; ++j) {
      int p = ty + j * 8;
      xbf[((long)b * HW_N + p0 + p) * C_N + c0 + tx] = __float2bfloat16(tile[tx * 33 + p]);
    }
    __syncthreads();
    if (ty == 0) {
      float tot = 0.f;
#pragma unroll
      for (int i = 0; i < 8; ++i) tot += part[i * 32 + tx];
      atomicAdd(&ssqx[b * HW_N + p0 + tx], tot);
    }
  } else {                                            // ---- ctx RMSNorm ----
    int row = (bid - 8192) * 4 + (tid >> 6);
    int lane = tid & 63;
    const float* cr = ctx + (long)row * C_N;
    float4 v0 = ((const float4*)cr)[lane * 2];
    float4 v1 = ((const float4*)cr)[lane * 2 + 1];
    float s = v0.x*v0.x + v0.y*v0.y + v0.z*v0.z + v0.w*v0.w
            + v1.x*v1.x + v1.y*v1.y + v1.z*v1.z + v1.w*v1.w;
#pragma unroll
    for (int m = 1; m < 64; m <<= 1) s += __shfl_xor(s, m);
    float r = rsqrtf(s * (1.0f / C_N) + EPSN);
    bf16 tmp[8];
    tmp[0] = __float2bfloat16(v0.x * r); tmp[1] = __float2bfloat16(v0.y * r);
    tmp[2] = __float2bfloat16(v0.z * r); tmp[3] = __float2bfloat16(v0.w * r);
    tmp[4] = __float2bfloat16(v1.x * r); tmp[5] = __float2bfloat16(v1.y * r);
    tmp[6] = __float2bfloat16(v1.z * r); tmp[7] = __float2bfloat16(v1.w * r);
    *reinterpret_cast<s16x8*>(cnbf + (long)row * C_N + lane * 8) =
        *reinterpret_cast<const s16x8*>(tmp);
  }
}

// ---------------- shared GEMM core: 128x128, BK=32, 2-phase dbuf, slot-XOR swizzle ----
__device__ __forceinline__ void gemm128_core(
    const bf16* __restrict__ A, const bf16* __restrict__ W, int K, int m0, int n0,
    bf16* sA, bf16* sB, f32x4 (&acc)[4][4])
{
  const int t = threadIdx.x;
  const int lane = t & 63, w = t >> 6;
  const int wm = (w >> 1) * 64, wn = (w & 1) * 64;
  const int lr = lane & 15, hi = lane >> 4;
  const int r = t >> 2, seg = t & 3;
  const int segsw = seg ^ ((r >> 1) & 3);           // inverse-swizzled global slot
  const long aoff0 = (long)(m0 + r) * K + segsw * 8;
  const long aoff1 = (long)(m0 + 64 + r) * K + segsw * 8;
  const long woff0 = (long)(n0 + r) * K + segsw * 8;
  const long woff1 = (long)(n0 + 64 + r) * K + segsw * 8;
  const int d0 = r * 32 + seg * 8, d1 = (64 + r) * 32 + seg * 8;  // linear LDS dest
  const int kofs = (hi ^ ((lr >> 1) & 3)) * 8;      // swizzled read slot

#define GSTAGE(buf, k0)                                           \
  do {                                                            \
    gload_lds16(A + aoff0 + (k0), &sA[(buf) * 4096 + d0]);        \
    gload_lds16(A + aoff1 + (k0), &sA[(buf) * 4096 + d1]);        \
    gload_lds16(W + woff0 + (k0), &sB[(buf) * 4096 + d0]);        \
    gload_lds16(W + woff1 + (k0), &sB[(buf) * 4096 + d1]);        \
  } while (0)

  GSTAGE(0, 0);
  __syncthreads();
  int cur = 0;
  for (int k0 = 0; k0 < K; k0 += 32) {
    if (k0 + 32 < K) GSTAGE(cur ^ 1, k0 + 32);      // next tile flies during compute
    s16x8 af[4], bfr[4];
#pragma unroll
    for (int mi = 0; mi < 4; ++mi)
      af[mi] = *reinterpret_cast<const s16x8*>(
          &sA[cur * 4096 + (wm + mi * 16 + lr) * 32 + kofs]);
#pragma unroll
    for (int ni = 0; ni < 4; ++ni)
      bfr[ni] = *reinterpret_cast<const s16x8*>(
          &sB[cur * 4096 + (wn + ni * 16 + lr) * 32 + kofs]);
    __builtin_amdgcn_s_setprio(1);
#pragma unroll
    for (int mi = 0; mi < 4; ++mi)
#pragma unroll
      for (int ni = 0; ni < 4; ++ni)
        acc[mi][ni] = mfma16(af[mi], bfr[ni], acc[mi][ni]);
    __builtin_amdgcn_s_setprio(0);
    __syncthreads();
    cur ^= 1;
  }
#undef GSTAGE
}

// ---------------- K2: fused Q + KV projection GEMM (768 blocks = 3/CU) ----------------
__global__ __launch_bounds__(256, 2)
void gemm_qkv(const bf16* __restrict__ xbf, const bf16* __restrict__ cnbf,
              const bf16* __restrict__ Wqg, const bf16* __restrict__ Wkvg,
              const float* __restrict__ ssqx,
              bf16* __restrict__ qbf, bf16* __restrict__ kvbf, bf16* __restrict__ vT)
{
  __shared__ bf16 sA[2 * 4096];
  __shared__ bf16 sB[2 * 4096];
  const int bid = blockIdx.x;
  const bf16 *A, *W;
  int m0, n0;
  bool isQ;
  if (bid < 256) {
    isQ = true;  A = xbf;  W = Wqg;
    m0 = (bid >> 2) * 128; n0 = (bid & 3) * 128;
  } else {
    isQ = false; A = cnbf; W = Wkvg;
    int b2 = bid - 256;
    m0 = (b2 >> 3) * 128; n0 = (b2 & 7) * 128;
  }
  f32x4 acc[4][4] = {};
  gemm128_core(A, W, C_N, m0, n0, sA, sB, acc);

  const int lane = threadIdx.x & 63, w = threadIdx.x >> 6;
  const int wm = (w >> 1) * 64, wn = (w & 1) * 64;
  const int lr = lane & 15, hi = lane >> 4;

  if (isQ) {
#pragma unroll
    for (int mi = 0; mi < 4; ++mi) {
#pragma unroll
      for (int rr = 0; rr < 4; ++rr) {
        int row = m0 + wm + mi * 16 + hi * 4 + rr;
        // per-pixel RMS scale commutes with GEMM; 0.125*log2(e) folded in
        float rsc = rsqrtf(ssqx[row] * (1.0f / C_N) + EPSN) * 0.18033688011112042f;
#pragma unroll
        for (int ni = 0; ni < 4; ++ni) {
          int col = n0 + wn + ni * 16 + lr;
          qbf[(long)row * HID_N + col] = __float2bfloat16(acc[mi][ni][rr] * rsc);
        }
      }
    }
  } else if (n0 < HID_N) {                            // K half (whole tile)
#pragma unroll
    for (int mi = 0; mi < 4; ++mi)
#pragma unroll
      for (int rr = 0; rr < 4; ++rr) {
        int row = m0 + wm + mi * 16 + hi * 4 + rr;
#pragma unroll
        for (int ni = 0; ni < 4; ++ni) {
          int col = n0 + wn + ni * 16 + lr;
          kvbf[(long)row * (2 * HID_N) + col] = __float2bfloat16(acc[mi][ni][rr]);
        }
      }
  } else {                                            // V half -> vT, s16x4 over rr
    const int bq = m0 >> 10;
    const int l0 = (m0 & 1023) + wm;
#pragma unroll
    for (int mi = 0; mi < 4; ++mi) {
#pragma unroll
      for (int ni = 0; ni < 4; ++ni) {
        int d = n0 - HID_N + wn + ni * 16 + lr;
        s16x4 pk;
#pragma unroll
        for (int rr = 0; rr < 4; ++rr) pk[rr] = (short)bfbits(acc[mi][ni][rr]);
        *reinterpret_cast<s16x4*>(
            &vT[((long)(bq * HID_N + d)) * LC_N + l0 + mi * 16 + hi * 4]) = pk;
      }
    }
  }
}

// ---------------- K3: fused flash attention ----------------
// Block = 4 waves, 128 q-rows, one (b,h); x = bh (XCD L2 locality). K/V tiles staged
// cooperatively (2-phase dbuf, global_load_lds, slot-XOR swizzle). Swapped QK^T;
// exp2 softmax (log2e folded in Q); defer-max THR=8.
__global__ __launch_bounds__(256, 2)
void attn_fused(const bf16* __restrict__ qbf, const bf16* __restrict__ kvbf,
                const bf16* __restrict__ vT, bf16* __restrict__ attno)
{
  __shared__ bf16 sK[2][4096];
  __shared__ bf16 sV[2][4096];
  __shared__ bf16 Pl[4][32 * 72];                   // per-wave P, stride 72 (pad)
  const int t = threadIdx.x;
  const int wv = t >> 6, lane = t & 63;
  const int lr = lane & 15, hi = lane >> 4;
  const int hi8 = hi * 8, hi4 = hi * 4;
  const int bh = blockIdx.x, b = bh >> 3, h = bh & 7;
  const int q_base = blockIdx.y * 128 + wv * 32;

  const bf16* kbase = kvbf + (long)b * LC_N * 1024 + h * DHEAD;
  const bf16* vbase = vT + ((long)b * HID_N + h * DHEAD) * (long)LC_N;
  bf16* Pw = Pl[wv];

  s16x8 qf[2][2];
#pragma unroll
  for (int qt = 0; qt < 2; ++qt)
#pragma unroll
    for (int c = 0; c < 2; ++c)
      qf[qt][c] = ld8(qbf + ((long)b * HW_N + q_base + qt * 16 + lr) * HID_N
                          + h * DHEAD + c * 32 + hi8);

  const int srow = lane >> 2;
  const int scol = ((lane & 3) ^ ((lane >> 3) & 3)) * 8;  // inverse-swizzled source
  const int rxofs = (hi ^ ((lr >> 1) & 3)) * 8;           // swizzled read slot

#define ASTAGE(buf, l0n)                                                        \
  do {                                                                          \
    _Pragma("unroll")                                                           \
    for (int j = 0; j < 4; ++j) {                                               \
      int lin = wv * 4 + j;                                                     \
      int cc = (lin >> 2) & 1, qq = lin & 3;                                    \
      if (lin < 8) {                                                            \
        gload_lds16(kbase + (long)((l0n) + qq * 16 + srow) * 1024 + cc * 32 + scol, \
                    &sK[buf][cc * 2048 + qq * 512 + lane * 8]);                 \
      } else {                                                                  \
        gload_lds16(vbase + (long)(qq * 16 + srow) * 1024 + (l0n) + cc * 32 + scol, \
                    &sV[buf][cc * 2048 + qq * 512 + lane * 8]);                 \
      }                                                                         \
    }                                                                           \
  } while (0)

  float m[2] = {-1e30f, -1e30f};
  float lsum[2] = {0.f, 0.f};
  f32x4 o[2][4] = {};

  ASTAGE(0, 0);
  __syncthreads();
  int cur = 0;

#pragma unroll 1
  for (int l0 = 0; l0 < LC_N; l0 += 64) {
    if (l0 + 64 < LC_N) ASTAGE(cur ^ 1, l0 + 64);

    f32x4 st[4][2] = {};
    __builtin_amdgcn_s_setprio(1);
#pragma unroll
    for (int kt = 0; kt < 4; ++kt) {
      s16x8 k0 = *reinterpret_cast<const s16x8*>(&sK[cur][(kt * 16 + lr) * 32 + rxofs]);
      s16x8 k1 = *reinterpret_cast<const s16x8*>(&sK[cur][2048 + (kt * 16 + lr) * 32 + rxofs]);
      st[kt][0] = mfma16(k0, qf[0][0], st[kt][0]);
      st[kt][0] = mfma16(k1, qf[0][1], st[kt][0]);
      st[kt][1] = mfma16(k0, qf[1][0], st[kt][1]);
      st[kt][1] = mfma16(k1, qf[1][1], st[kt][1]);
    }
    __builtin_amdgcn_s_setprio(0);

    float pmax[2];
#pragma unroll
    for (int qt = 0; qt < 2; ++qt) {
      float mx = st[0][qt][0];
#pragma unroll
      for (int kt = 0; kt < 4; ++kt)
#pragma unroll
        for (int rr = 0; rr < 4; ++rr)
          mx = fmaxf(mx, st[kt][qt][rr]);
      pmax[qt] = mx;
    }
    bool ok = (pmax[0] <= m[0] + 8.f) && (pmax[1] <= m[1] + 8.f);
    if (!__all(ok)) {
#pragma unroll
      for (int qt = 0; qt < 2; ++qt) {
        float rm = pmax[qt];
        rm = fmaxf(rm, __shfl_xor(rm, 16));
        rm = fmaxf(rm, __shfl_xor(rm, 32));
        float mn = fmaxf(m[qt], rm);
        float al = __builtin_amdgcn_exp2f(m[qt] - mn);
        m[qt] = mn;
        lsum[qt] *= al;
        float arr[4];
#pragma unroll
        for (int rr = 0; rr < 4; ++rr) arr[rr] = __shfl(al, hi4 + rr);
#pragma unroll
        for (int dt = 0; dt < 4; ++dt)
#pragma unroll
          for (int rr = 0; rr < 4; ++rr) o[qt][dt][rr] *= arr[rr];
      }
    }

#pragma unroll
    for (int qt = 0; qt < 2; ++qt) {
      float ls = 0.f;
#pragma unroll
      for (int kt = 0; kt < 4; ++kt) {
        float p0 = __builtin_amdgcn_exp2f(st[kt][qt][0] - m[qt]);
        float p1 = __builtin_amdgcn_exp2f(st[kt][qt][1] - m[qt]);
        float p2 = __builtin_amdgcn_exp2f(st[kt][qt][2] - m[qt]);
        float p3 = __builtin_amdgcn_exp2f(st[kt][qt][3] - m[qt]);
        ls += (p0 + p1) + (p2 + p3);
        s16x4 pk;
        pk[0] = (short)bfbits(p0); pk[1] = (short)bfbits(p1);
        pk[2] = (short)bfbits(p2); pk[3] = (short)bfbits(p3);
        *reinterpret_cast<s16x4*>(&Pw[(qt * 16 + lr) * 72 + kt * 16 + hi4]) = pk;
      }
      lsum[qt] += ls;
    }

    __builtin_amdgcn_s_setprio(1);
#pragma unroll
    for (int c = 0; c < 2; ++c) {
      s16x8 pa0 = *reinterpret_cast<const s16x8*>(&Pw[(0 * 16 + lr) * 72 + c * 32 + hi8]);
      s16x8 pa1 = *reinterpret_cast<const s16x8*>(&Pw[(1 * 16 + lr) * 72 + c * 32 + hi8]);
#pragma unroll
      for (int dt = 0; dt < 4; ++dt) {
        s16x8 vv = *reinterpret_cast<const s16x8*>(
            &sV[cur][c * 2048 + (dt * 16 + lr) * 32 + rxofs]);
        o[0][dt] = mfma16(pa0, vv, o[0][dt]);
        o[1][dt] = mfma16(pa1, vv, o[1][dt]);
      }
    }
    __builtin_amdgcn_s_setprio(0);

    __syncthreads();
    cur ^= 1;
  }
#undef ASTAGE

#pragma unroll
  for (int qt = 0; qt < 2; ++qt) {
    float ls = lsum[qt];
    ls += __shfl_xor(ls, 16);
    ls += __shfl_xor(ls, 32);
    float linv[4];
#pragma unroll
    for (int rr = 0; rr < 4; ++rr) linv[rr] = 1.f / __shfl(ls, hi4 + rr);
#pragma unroll
    for (int dt = 0; dt < 4; ++dt)
#pragma unroll
      for (int rr = 0; rr < 4; ++rr)
        attno[((long)b * HW_N + q_base + qt * 16 + hi4 + rr) * HID_N
              + h * DHEAD + dt * 16 + lr] = __float2bfloat16(o[qt][dt][rr] * linv[rr]);
  }
}

// ---------------- K4: O-projection GEMM + bias + row sum-of-squares ----------------
__global__ __launch_bounds__(256, 2)
void gemm_o(const bf16* __restrict__ attno, const bf16* __restrict__ Wob,
            const float* __restrict__ bo, float* __restrict__ ytmp,
            float* __restrict__ ssqy)
{
  __shared__ bf16 sA[2 * 4096];
  __shared__ bf16 sB[2 * 4096];
  const int m0 = (blockIdx.x >> 2) * 128;
  const int n0 = (blockIdx.x & 3) * 128;
  f32x4 acc[4][4] = {};
  gemm128_core(attno, Wob, HID_N, m0, n0, sA, sB, acc);

  const int lane = threadIdx.x & 63, w = threadIdx.x >> 6;
  const int wm = (w >> 1) * 64, wn = (w & 1) * 64;
  const int lr = lane & 15, hi = lane >> 4;
  float ss[4][4];
#pragma unroll
  for (int mi = 0; mi < 4; ++mi)
#pragma unroll
    for (int rr = 0; rr < 4; ++rr) ss[mi][rr] = 0.f;

#pragma unroll
  for (int mi = 0; mi < 4; ++mi) {
#pragma unroll
    for (int ni = 0; ni < 4; ++ni) {
      float bb = bo[n0 + wn + ni * 16 + lr];
#pragma unroll
      for (int rr = 0; rr < 4; ++rr) {
        int row = m0 + wm + mi * 16 + hi * 4 + rr;
        int col = n0 + wn + ni * 16 + lr;
        float v = acc[mi][ni][rr] + bb;
        ytmp[(long)row * C_N + col] = v;
        ss[mi][rr] += v * v;
      }
    }
  }
#pragma unroll
  for (int mi = 0; mi < 4; ++mi)
#pragma unroll
    for (int rr = 0; rr < 4; ++rr) {
      float s = ss[mi][rr];
      s += __shfl_xor(s, 1); s += __shfl_xor(s, 2);
      s += __shfl_xor(s, 4); s += __shfl_xor(s, 8);
      if (lr == 0) atomicAdd(&ssqy[m0 + wm + mi * 16 + hi * 4 + rr], s);
    }
}

// ---------------- K5: final transpose + norm + residual ----------------
__global__ __launch_bounds__(256) void final_kernel(
    const float* __restrict__ ytmp, const float* __restrict__ g2,
    const float* __restrict__ ssqy, const float* __restrict__ x,
    float* __restrict__ out)
{
  __shared__ float tile[32 * 33];
  const int t = blockIdx.x;
  int b = t >> 9, c0 = ((t >> 5) & 15) * 32, p0 = (t & 31) * 32;
  int tx = threadIdx.x & 31, ty = threadIdx.x >> 5;
#pragma unroll
  for (int j = 0; j < 4; ++j) {
    int p = ty + j * 8;
    tile[p * 33 + tx] = ytmp[((long)b * HW_N + p0 + p) * C_N + c0 + tx];
  }
  __syncthreads();
  float r = rsqrtf(ssqy[b * HW_N + p0 + tx] * (1.0f / C_N) + EPSN);
#pragma unroll
  for (int j = 0; j < 4; ++j) {
    int c = ty + j * 8;
    long oidx = ((long)b * C_N + c0 + c) * HW_N + p0 + tx;
    out[oidx] = tile[tx * 33 + c] * r * g2[c0 + c] + x[oidx];
  }
}

// ---------------- launch ----------------
extern "C" void kernel_launch(void* const* d_in, const int* in_sizes, int n_in,
                              void* d_out, int out_size, void* d_ws, size_t ws_size,
                              hipStream_t stream) {
  const float* x   = (const float*)d_in[0];
  const float* ctx = (const float*)d_in[1];
  const float* Wq  = (const float*)d_in[2];
  const float* Wkv = (const float*)d_in[3];
  const float* Wo  = (const float*)d_in[4];
  const float* bo  = (const float*)d_in[5];
  const float* g   = (const float*)d_in[6];
  const float* g2  = (const float*)d_in[7];
  float* out = (float*)d_out;

  char* ws = (char*)d_ws;
  bf16*  Wqg   = (bf16*)(ws + 0);          //  524288
  bf16*  Wkvg  = (bf16*)(ws + 524288);     // 1048576
  bf16*  Wob   = (bf16*)(ws + 1572864);    //  524288
  float* ssqx  = (float*)(ws + 2097152);   //  32768
  float* ssqy  = (float*)(ws + 2129920);   //  32768
  bf16*  xbf   = (bf16*)(ws + 2162688);    // 8388608
  bf16*  cnbf  = (bf16*)(ws + 10551296);   // 8388608
  bf16*  qbf   = (bf16*)(ws + 18939904);   // 8388608
  bf16*  kvbf  = (bf16*)(ws + 27328512);   // 16777216
  bf16*  vT    = (bf16*)(ws + 44105728);   // 8388608
  bf16*  attno = (bf16*)(ws + 52494336);   // 8388608
  float* ytmp  = (float*)(ws + 2162688);   // aliases xbf+cnbf (dead by gemm_o)

  init_kernel<<<32, 256, 0, stream>>>(ssqx, ssqy);
  pre_kernel<<<10240, 256, 0, stream>>>(x, ctx, Wq, Wkv, Wo, g,
                                        Wqg, Wkvg, Wob, xbf, cnbf, ssqx);
  gemm_qkv<<<768, 256, 0, stream>>>(xbf, cnbf, Wqg, Wkvg, ssqx, qbf, kvbf, vT);
  attn_fused<<<dim3(64, 8), 256, 0, stream>>>(qbf, kvbf, vT, attno);
  gemm_o<<<256, 256, 0, stream>>>(attno, Wob, bo, ytmp, ssqy);
  final_kernel<<<4096, 256, 0, stream>>>(ytmp, g2, ssqy, x, out);
}